// Round 2
// baseline (216.762 us; speedup 1.0000x reference)
//
#include <hip/hip_runtime.h>
#include <cmath>

namespace {

constexpr int Bn = 4;
constexpr int Cn = 3;
constexpr int Hn = 32, Wn = 32, Dn = 32;
constexpr int Kn = 16;
constexpr int Sn = 16;
constexpr int HOn = 30;
constexpr int Pn = HOn * HOn * HOn;       // 27000
constexpr int XCH = Hn * Wn * Dn;          // 32768 (one channel)
constexpr int XB  = Cn * XCH;              // 98304 (one batch)

__device__ __constant__ float kMops[16][4] = {
    {0, 0, 0, 0},  {0, 0, 0, 1},  {0, 1, 0, -1}, {0, 1, 0, 0},
    {0, 0, 1, -1}, {0, 0, 1, 0},  {0, 1, 1, -2}, {0, 1, 1, -1},
    {1, -1, -1, 1},{1, -1, -1, 2},{1, 0, -1, 0}, {1, 0, -1, 1},
    {1, -1, 0, 0}, {1, -1, 0, 1}, {1, 0, 0, -1}, {1, 0, 0, 0}};

__global__ __launch_bounds__(256)
void logic_conv3d(const float* __restrict__ x,
                  const int* __restrict__ idx_a,
                  const int* __restrict__ idx_b,
                  const float* __restrict__ w0,
                  const float* __restrict__ w1,
                  const float* __restrict__ w2,
                  const float* __restrict__ w3,
                  const float* __restrict__ w4,
                  float* __restrict__ out) {
    const int k = blockIdx.y;
    const int b = blockIdx.z;   // batch split: tree is independent per batch
    const int tid = threadIdx.x;

    // 31 coefficient rows (float4 -> one ds_read_b128 each):
    // lvl0 n=0..15 -> rows 0..15, lvl1 -> 16..23, lvl2 -> 24..27,
    // lvl3 -> 28..29, lvl4 -> 30.
    __shared__ float4 coef4[31];

    if (tid < 31) {
        const float* wl;
        int n;
        if (tid < 16)      { wl = w0; n = tid; }
        else if (tid < 24) { wl = w1; n = tid - 16; }
        else if (tid < 28) { wl = w2; n = tid - 24; }
        else if (tid < 30) { wl = w3; n = tid - 28; }
        else               { wl = w4; n = 0; }
        const float* row = wl + (n * Kn + k) * 16;  // w_l[n, k, :]
        float e[16];
        float mx = row[0];
        #pragma unroll
        for (int o = 1; o < 16; ++o) mx = fmaxf(mx, row[o]);
        float sum = 0.f;
        #pragma unroll
        for (int o = 0; o < 16; ++o) { e[o] = expf(row[o] - mx); sum += e[o]; }
        const float inv = 1.0f / sum;
        float4 c;
        float acc;
        acc = 0.f;
        #pragma unroll
        for (int o = 0; o < 16; ++o) acc += e[o] * kMops[o][0];
        c.x = acc * inv;
        acc = 0.f;
        #pragma unroll
        for (int o = 0; o < 16; ++o) acc += e[o] * kMops[o][1];
        c.y = acc * inv;
        acc = 0.f;
        #pragma unroll
        for (int o = 0; o < 16; ++o) acc += e[o] * kMops[o][2];
        c.z = acc * inv;
        acc = 0.f;
        #pragma unroll
        for (int o = 0; o < 16; ++o) acc += e[o] * kMops[o][3];
        c.w = acc * inv;
        coef4[tid] = c;
    }
    __syncthreads();

    const int p = blockIdx.x * blockDim.x + tid;
    if (p >= Pn) return;

    // p = h0*900 + w0*30 + d0  (meshgrid 'ij', d fastest)
    const int h0 = p / 900;
    const int rem = p - h0 * 900;
    const int w0i = rem / 30;
    const int d0 = rem - w0i * 30;
    const int poff = h0 * (Wn * Dn) + w0i * Dn + d0;

    const float* __restrict__ xb = x + (size_t)b * XB;

    // idx_a[k, p=0, s, :] == pa[k, s] because off[0] == (0,0,0,0) (PAD=0).
    // Bases depend only on k (block-uniform): compute from uniform loads and
    // seal into SGPRs via readfirstlane so each gather is
    //   global_load_dword v, v_poff, s[base]   (scalar base, ~0 VALU addr).
    const int* __restrict__ idxa_k = idx_a + (size_t)k * Pn * Sn * 4;
    const int* __restrict__ idxb_k = idx_b + (size_t)k * Pn * Sn * 4;

    float v[16];

    // Level 0: 32 scalar-base gather loads per thread, all independent.
    #pragma unroll
    for (int s = 0; s < 16; ++s) {
        const int4 ia = *reinterpret_cast<const int4*>(idxa_k + s * 4);
        const int4 ib = *reinterpret_cast<const int4*>(idxb_k + s * 4);
        const int ba = __builtin_amdgcn_readfirstlane(
            ia.w * XCH + ia.x * (Wn * Dn) + ia.y * Dn + ia.z);
        const int bbb = __builtin_amdgcn_readfirstlane(
            ib.w * XCH + ib.x * (Wn * Dn) + ib.y * Dn + ib.z);
        const float* __restrict__ xa = xb + ba;
        const float* __restrict__ xbp = xb + bbb;
        const float a  = xa[poff];
        const float bb = xbp[poff];
        const float4 c = coef4[s];
        v[s] = c.x + c.y * a + c.z * bb + c.w * (a * bb);
    }
    #pragma unroll
    for (int n = 0; n < 8; ++n) {
        const float4 c = coef4[16 + n];
        const float a = v[2 * n], bb = v[2 * n + 1];
        v[n] = c.x + c.y * a + c.z * bb + c.w * (a * bb);
    }
    #pragma unroll
    for (int n = 0; n < 4; ++n) {
        const float4 c = coef4[24 + n];
        const float a = v[2 * n], bb = v[2 * n + 1];
        v[n] = c.x + c.y * a + c.z * bb + c.w * (a * bb);
    }
    #pragma unroll
    for (int n = 0; n < 2; ++n) {
        const float4 c = coef4[28 + n];
        const float a = v[2 * n], bb = v[2 * n + 1];
        v[n] = c.x + c.y * a + c.z * bb + c.w * (a * bb);
    }
    {
        const float4 c = coef4[30];
        const float a = v[0], bb = v[1];
        const float res = c.x + c.y * a + c.z * bb + c.w * (a * bb);
        out[((size_t)b * Kn + k) * Pn + p] = res;
    }
}

}  // namespace

extern "C" void kernel_launch(void* const* d_in, const int* in_sizes, int n_in,
                              void* d_out, int out_size, void* d_ws, size_t ws_size,
                              hipStream_t stream) {
    const float* x     = (const float*)d_in[0];
    const int*   idx_a = (const int*)d_in[1];
    const int*   idx_b = (const int*)d_in[2];
    const float* w0    = (const float*)d_in[3];
    const float* w1    = (const float*)d_in[4];
    const float* w2    = (const float*)d_in[5];
    const float* w3    = (const float*)d_in[6];
    const float* w4    = (const float*)d_in[7];
    float* out = (float*)d_out;

    dim3 grid((Pn + 255) / 256, Kn, Bn);
    hipLaunchKernelGGL(logic_conv3d, grid, dim3(256), 0, stream,
                       x, idx_a, idx_b, w0, w1, w2, w3, w4, out);
}

// Round 3
// 207.752 us; speedup vs baseline: 1.0434x; 1.0434x over previous
//
#include <hip/hip_runtime.h>
#include <cmath>

namespace {

constexpr int Bn = 4;
constexpr int Cn = 3;
constexpr int Hn = 32, Wn = 32, Dn = 32;
constexpr int Kn = 16;
constexpr int Sn = 16;
constexpr int HOn = 30;
constexpr int Pn = HOn * HOn * HOn;       // 27000
constexpr int XCH = Hn * Wn * Dn;          // 32768 (one channel)
constexpr int XB  = Cn * XCH;              // 98304 (one batch)
constexpr int NODES = 31;                  // 16 + 8 + 4 + 2 + 1 tree nodes

// Workspace layout (d_ws):
//   [0, 7936)            float4 coef[Kn][NODES]
//   [7936, 8960)         int    base_a[Kn][Sn]
//   [8960, 9984)         int    base_b[Kn][Sn]
constexpr int kCoefBytes = Kn * NODES * 16;          // 7936
constexpr int kBaseInts  = Kn * Sn;                  // 256

__device__ __constant__ float kMops[16][4] = {
    {0, 0, 0, 0},  {0, 0, 0, 1},  {0, 1, 0, -1}, {0, 1, 0, 0},
    {0, 0, 1, -1}, {0, 0, 1, 0},  {0, 1, 1, -2}, {0, 1, 1, -1},
    {1, -1, -1, 1},{1, -1, -1, 2},{1, 0, -1, 0}, {1, 0, -1, 1},
    {1, -1, 0, 0}, {1, -1, 0, 1}, {1, 0, 0, -1}, {1, 0, 0, 0}};

// One block per k (16 blocks x 64 threads). tid<31: coef node; tid in
// [32,48): gather-base pair. Runs once; cost ~1-2 us total.
__global__ __launch_bounds__(64)
void precompute(const int* __restrict__ idx_a,
                const int* __restrict__ idx_b,
                const float* __restrict__ w0,
                const float* __restrict__ w1,
                const float* __restrict__ w2,
                const float* __restrict__ w3,
                const float* __restrict__ w4,
                float4* __restrict__ coef,
                int* __restrict__ base_a,
                int* __restrict__ base_b) {
    const int k = blockIdx.x;
    const int tid = threadIdx.x;

    if (tid < NODES) {
        const float* wl;
        int n;
        if (tid < 16)      { wl = w0; n = tid; }
        else if (tid < 24) { wl = w1; n = tid - 16; }
        else if (tid < 28) { wl = w2; n = tid - 24; }
        else if (tid < 30) { wl = w3; n = tid - 28; }
        else               { wl = w4; n = 0; }
        const float* row = wl + (n * Kn + k) * 16;  // w_l[n, k, :]
        float e[16];
        float mx = row[0];
        #pragma unroll
        for (int o = 1; o < 16; ++o) mx = fmaxf(mx, row[o]);
        float sum = 0.f;
        #pragma unroll
        for (int o = 0; o < 16; ++o) { e[o] = expf(row[o] - mx); sum += e[o]; }
        const float inv = 1.0f / sum;
        float4 c;
        float acc;
        acc = 0.f;
        #pragma unroll
        for (int o = 0; o < 16; ++o) acc += e[o] * kMops[o][0];
        c.x = acc * inv;
        acc = 0.f;
        #pragma unroll
        for (int o = 0; o < 16; ++o) acc += e[o] * kMops[o][1];
        c.y = acc * inv;
        acc = 0.f;
        #pragma unroll
        for (int o = 0; o < 16; ++o) acc += e[o] * kMops[o][2];
        c.z = acc * inv;
        acc = 0.f;
        #pragma unroll
        for (int o = 0; o < 16; ++o) acc += e[o] * kMops[o][3];
        c.w = acc * inv;
        coef[k * NODES + tid] = c;
    } else if (tid >= 32 && tid < 32 + Sn) {
        const int s = tid - 32;
        // idx_a[k, p=0, s, :] == pa[k, s] because off[0] == (0,0,0,0).
        const int* pa = idx_a + (((size_t)k * Pn) * Sn + s) * 4;
        const int* pb = idx_b + (((size_t)k * Pn) * Sn + s) * 4;
        base_a[k * Sn + s] = pa[3] * XCH + pa[0] * (Wn * Dn) + pa[1] * Dn + pa[2];
        base_b[k * Sn + s] = pb[3] * XCH + pb[0] * (Wn * Dn) + pb[1] * Dn + pb[2];
    }
}

// Main kernel: no LDS, no __syncthreads, no softmax. All block-uniform data
// arrives via uniform const-__restrict__ loads (compiler scalarizes to
// s_load -> SGPR broadcast); gather bases additionally sealed into SGPRs
// with readfirstlane so each gather is global_load_dword v, v_poff, s[base].
__global__ __launch_bounds__(256)
void logic_conv3d(const float* __restrict__ x,
                  const float4* __restrict__ coef,
                  const int* __restrict__ base_a,
                  const int* __restrict__ base_b,
                  float* __restrict__ out) {
    const int k = blockIdx.y;
    const int b = blockIdx.z;
    const int p = blockIdx.x * blockDim.x + threadIdx.x;
    if (p >= Pn) return;

    // p = h0*900 + w0*30 + d0  (meshgrid 'ij', d fastest)
    const int h0 = p / 900;
    const int rem = p - h0 * 900;
    const int w0i = rem / 30;
    const int d0 = rem - w0i * 30;
    const int poff = h0 * (Wn * Dn) + w0i * Dn + d0;

    const float* __restrict__ xb = x + (size_t)b * XB;
    const float4* __restrict__ ck = coef + k * NODES;
    const int* __restrict__ bak = base_a + k * Sn;
    const int* __restrict__ bbk = base_b + k * Sn;

    float v[16];

    // Level 0: 32 scalar-base gathers, all independent.
    #pragma unroll
    for (int s = 0; s < 16; ++s) {
        const int ba = __builtin_amdgcn_readfirstlane(bak[s]);
        const int bbo = __builtin_amdgcn_readfirstlane(bbk[s]);
        const float a  = xb[ba + poff];
        const float bv = xb[bbo + poff];
        const float4 c = ck[s];
        v[s] = c.x + c.y * a + c.z * bv + c.w * (a * bv);
    }
    #pragma unroll
    for (int n = 0; n < 8; ++n) {
        const float4 c = ck[16 + n];
        const float a = v[2 * n], bv = v[2 * n + 1];
        v[n] = c.x + c.y * a + c.z * bv + c.w * (a * bv);
    }
    #pragma unroll
    for (int n = 0; n < 4; ++n) {
        const float4 c = ck[24 + n];
        const float a = v[2 * n], bv = v[2 * n + 1];
        v[n] = c.x + c.y * a + c.z * bv + c.w * (a * bv);
    }
    #pragma unroll
    for (int n = 0; n < 2; ++n) {
        const float4 c = ck[28 + n];
        const float a = v[2 * n], bv = v[2 * n + 1];
        v[n] = c.x + c.y * a + c.z * bv + c.w * (a * bv);
    }
    {
        const float4 c = ck[30];
        const float a = v[0], bv = v[1];
        const float res = c.x + c.y * a + c.z * bv + c.w * (a * bv);
        out[((size_t)b * Kn + k) * Pn + p] = res;
    }
}

}  // namespace

extern "C" void kernel_launch(void* const* d_in, const int* in_sizes, int n_in,
                              void* d_out, int out_size, void* d_ws, size_t ws_size,
                              hipStream_t stream) {
    const float* x     = (const float*)d_in[0];
    const int*   idx_a = (const int*)d_in[1];
    const int*   idx_b = (const int*)d_in[2];
    const float* w0    = (const float*)d_in[3];
    const float* w1    = (const float*)d_in[4];
    const float* w2    = (const float*)d_in[5];
    const float* w3    = (const float*)d_in[6];
    const float* w4    = (const float*)d_in[7];
    float* out = (float*)d_out;

    float4* coef   = (float4*)d_ws;
    int*    base_a = (int*)((char*)d_ws + kCoefBytes);
    int*    base_b = base_a + kBaseInts;

    hipLaunchKernelGGL(precompute, dim3(Kn), dim3(64), 0, stream,
                       idx_a, idx_b, w0, w1, w2, w3, w4, coef, base_a, base_b);

    dim3 grid((Pn + 255) / 256, Kn, Bn);
    hipLaunchKernelGGL(logic_conv3d, grid, dim3(256), 0, stream,
                       x, coef, base_a, base_b, out);
}